// Round 5
// baseline (207.200 us; speedup 1.0000x reference)
//
#include <hip/hip_runtime.h>
#include <math.h>

#define KSZ   17
#define PADR  8
#define FDIM  100
#define ODIM  180
#define HTOT  512
#define WTOT  512
#define TILE  16
#define LDSW  48
#define NSLICE 8
#define SLICE_SZ 2250      // 18000 filters / 8 slices -> 2.6 MB, fits one XCD's 4 MiB L2
#define TEMPERATURE 20.0f
#define THRESHOLD   55.0f

// ---- order-preserving float<->uint encoding for atomic min/max ----
__device__ __forceinline__ unsigned int fenc(float f) {
    unsigned int u = __float_as_uint(f);
    return (u & 0x80000000u) ? ~u : (u | 0x80000000u);
}
__device__ __forceinline__ float fdec(unsigned int k) {
    unsigned int u = (k & 0x80000000u) ? (k ^ 0x80000000u) : ~k;
    return __uint_as_float(u);
}

// One block = (tile, slice). slice = gid & 7 lands on XCD (gid % 8) under
// round-robin dispatch, so XCD s only streams filters [s*2250, (s+1)*2250) —
// a 2.6 MB working set that stays resident in that XCD's 4 MiB L2.
__global__ __launch_bounds__(256) void filter_sliced(
    const float* __restrict__ x,
    const int*   __restrict__ freq,
    const int*   __restrict__ orient,
    const float* __restrict__ fb,
    float*       __restrict__ y,
    unsigned int* __restrict__ mm)
{
    __shared__ float tile[2 * TILE][LDSW];     // 32 x 48 floats
    __shared__ int   sidx[256];                // per-pixel filter index
    __shared__ unsigned short sel[256];        // compacted list of my-slice pixels
    __shared__ unsigned int nsel;

    const int gid   = blockIdx.x;
    const int slice = gid & (NSLICE - 1);
    const int t     = gid >> 3;                // tile id 0..1023
    const int bx    = t & 31, by = t >> 5;
    const int tid   = threadIdx.x;
    const int px    = tid & 15, py = tid >> 4;

    const int pid = (by * TILE + py) * WTOT + bx * TILE + px;
    int f0 = freq[pid] - 1;
    int o0 = orient[pid] - 1;
    f0 = f0 < 0 ? 0 : (f0 > FDIM - 1 ? FDIM - 1 : f0);
    o0 = o0 < 0 ? 0 : (o0 > ODIM - 1 ? ODIM - 1 : o0);
    const int idx = f0 * ODIM + o0;
    sidx[tid] = idx;
    if (tid == 0) nsel = 0;
    __syncthreads();

    // compact the pixels belonging to this block's slice
    const int lo = slice * SLICE_SZ;
    if (idx >= lo && idx < lo + SLICE_SZ) {
        unsigned int s = atomicAdd(&nsel, 1u);
        sel[s] = (unsigned short)tid;
    }

    // stage 32x32 input region (zero-padded at image borders)
    const int h0 = by * TILE - PADR;
    const int w0 = bx * TILE - PADR;
    for (int i = tid; i < 32 * 32; i += 256) {
        const int r = i >> 5, c = i & 31;
        const int gh = h0 + r, gw = w0 + c;
        float v = 0.f;
        if (gh >= 0 && gh < HTOT && gw >= 0 && gw < WTOT)
            v = x[gh * WTOT + gw];
        tile[r][c] = v;
    }
    __syncthreads();

    const unsigned int m = nsel;
    const int l  = tid & 15;                   // lane within quarter-wave
    const int qw = tid >> 4;                   // quarter-wave id

    int offs[18];
    #pragma unroll
    for (int j = 0; j < 18; ++j) {
        const int e = j * 16 + l;
        offs[j] = (e / 17) * LDSW + (e % 17);
    }

    float mn = 3.4e38f, mx = -3.4e38f;

    // each quarter-wave takes every 16th selected pixel (avg ~2 each)
    for (unsigned int s = qw; s < m; s += 16) {
        const int tp  = sel[s];
        const int ppy = tp >> 4, ppx = tp & 15;
        const float* __restrict__ kf   = fb + (size_t)sidx[tp] * 289;
        const float* __restrict__ base = &tile[ppy][ppx];

        float a0 = 0.f, a1 = 0.f, a2 = 0.f, a3 = 0.f;
        #pragma unroll
        for (int j = 0; j < 16; j += 4) {
            a0 = fmaf(kf[(j    ) * 16 + l], base[offs[j    ]], a0);
            a1 = fmaf(kf[(j + 1) * 16 + l], base[offs[j + 1]], a1);
            a2 = fmaf(kf[(j + 2) * 16 + l], base[offs[j + 2]], a2);
            a3 = fmaf(kf[(j + 3) * 16 + l], base[offs[j + 3]], a3);
        }
        a0 = fmaf(kf[16 * 16 + l], base[offs[16]], a0);
        a1 = fmaf(kf[17 * 16 + l], base[offs[17]], a1);
        float acc = (a0 + a1) + (a2 + a3);
        if (l == 0) acc = fmaf(kf[288], base[16 * LDSW + 16], acc);  // e = 288 tail

        // butterfly sum over the 16-lane group
        #pragma unroll
        for (int off = 8; off; off >>= 1)
            acc += __shfl_xor(acc, off, 64);

        if (l == 0)
            y[(by * TILE + ppy) * WTOT + bx * TILE + ppx] = acc;
        mn = fminf(mn, acc);
        mx = fmaxf(mx, acc);
    }

    // ---- block min/max reduce, one atomic pair per block ----
    #pragma unroll
    for (int off = 32; off > 0; off >>= 1) {
        mn = fminf(mn, __shfl_down(mn, off, 64));
        mx = fmaxf(mx, __shfl_down(mx, off, 64));
    }
    __shared__ float smn[4], smx[4];
    const int wid = tid >> 6, lane = tid & 63;
    if (lane == 0) { smn[wid] = mn; smx[wid] = mx; }
    __syncthreads();
    if (tid == 0) {
        float bmn = smn[0], bmx = smx[0];
        #pragma unroll
        for (int i = 1; i < 4; ++i) {
            bmn = fminf(bmn, smn[i]);
            bmx = fmaxf(bmx, smx[i]);
        }
        atomicMin(&mm[0], fenc(bmn));
        atomicMax(&mm[1], fenc(bmx));
    }
}

__global__ __launch_bounds__(256) void filter_final(
    float* __restrict__ y,
    const unsigned int* __restrict__ mm)
{
    const int i = blockIdx.x * 256 + threadIdx.x;
    const float ymin = fdec(mm[0]);
    const float ymax = fdec(mm[1]);
    const float rng  = fmaxf(ymax - ymin, 1e-8f);

    const float v  = y[i];
    const float o1 = 100.f * (v - ymin) / rng;                     // in [0,100]
    const float s  = 100.f / (1.f + expf(-(TEMPERATURE * (o1 * 0.01f - THRESHOLD * 0.01f))));

    // analytic post-sigmoid extrema: o1 hits exactly 0 and 100 at argmin/argmax
    const float smin = 100.f / (1.f + expf( 11.f));   // 100*sigmoid(-11)
    const float smax = 100.f / (1.f + expf(-9.f));    // 100*sigmoid(+9)
    const float srng = fmaxf(smax - smin, 1e-8f);

    y[i] = 100.f * (s - smin) / srng;
}

extern "C" void kernel_launch(void* const* d_in, const int* in_sizes, int n_in,
                              void* d_out, int out_size, void* d_ws, size_t ws_size,
                              hipStream_t stream) {
    const float* x      = (const float*)d_in[0];
    const int*   freq   = (const int*)d_in[1];
    const int*   orient = (const int*)d_in[2];
    const float* fb     = (const float*)d_in[3];
    float*       out    = (float*)d_out;           // doubles as y scratch
    unsigned int* mm    = (unsigned int*)d_ws;     // [0]=enc(min), [1]=enc(max)

    hipMemsetAsync(mm, 0xFF, 4, stream);
    hipMemsetAsync((char*)d_ws + 4, 0x00, 4, stream);

    // 1024 tiles x 8 slices; consecutive gid = same tile across the 8 XCDs
    filter_sliced<<<dim3(1024 * NSLICE), 256, 0, stream>>>(x, freq, orient, fb, out, mm);

    filter_final<<<(HTOT * WTOT) / 256, 256, 0, stream>>>(out, mm);
}

// Round 6
// 43.990 us; speedup vs baseline: 4.7102x; 4.7102x over previous
//
#include <hip/hip_runtime.h>
#include <math.h>

#define KSZ   17
#define PADR  8
#define FDIM  100
#define ODIM  180
#define HTOT  512
#define WTOT  512
#define TILE  16
#define LDSW  48
#define NSLICE 8
#define SLICE_SZ 2250      // 18000/8 -> 2.6 MB per slice, fits one XCD's 4 MiB L2
#define NCELL 64           // partial min/max cells, each on its own 64-B line
#define TEMPERATURE 20.0f
#define THRESHOLD   55.0f

// ---- order-preserving float<->uint encoding for atomic min/max ----
__device__ __forceinline__ unsigned int fenc(float f) {
    unsigned int u = __float_as_uint(f);
    return (u & 0x80000000u) ? ~u : (u | 0x80000000u);
}
__device__ __forceinline__ float fdec(unsigned int k) {
    unsigned int u = (k & 0x80000000u) ? (k ^ 0x80000000u) : ~k;
    return __uint_as_float(u);
}

// ws layout (bytes):
//   [0,      4096)  : 64 encoded-min cells, stride 64 B, init 0xFF
//   [4096,   8192)  : 64 encoded-max cells, stride 64 B, init 0x00
//   [8192,   8200)  : final float {min, max} written by reduce_mm
__global__ __launch_bounds__(256) void filter_sliced(
    const float* __restrict__ x,
    const int*   __restrict__ freq,
    const int*   __restrict__ orient,
    const float* __restrict__ fb,
    float*       __restrict__ y,
    unsigned int* __restrict__ cells)
{
    __shared__ float tile[2 * TILE][LDSW];     // 32 x 48 floats
    __shared__ int   sidx[256];                // per-pixel filter index
    __shared__ unsigned short sel[256];        // compacted list of my-slice pixels
    __shared__ unsigned int nsel;

    const int gid   = blockIdx.x;
    const int slice = gid & (NSLICE - 1);
    const int t     = gid >> 3;                // tile id 0..1023
    const int bx    = t & 31, by = t >> 5;
    const int tid   = threadIdx.x;
    const int px    = tid & 15, py = tid >> 4;

    const int pid = (by * TILE + py) * WTOT + bx * TILE + px;
    int f0 = freq[pid] - 1;
    int o0 = orient[pid] - 1;
    f0 = f0 < 0 ? 0 : (f0 > FDIM - 1 ? FDIM - 1 : f0);
    o0 = o0 < 0 ? 0 : (o0 > ODIM - 1 ? ODIM - 1 : o0);
    const int idx = f0 * ODIM + o0;
    sidx[tid] = idx;
    if (tid == 0) nsel = 0;
    __syncthreads();

    // compact the pixels belonging to this block's slice
    const int lo = slice * SLICE_SZ;
    if (idx >= lo && idx < lo + SLICE_SZ) {
        unsigned int s = atomicAdd(&nsel, 1u);
        sel[s] = (unsigned short)tid;
    }

    // stage 32x32 input region (zero-padded at image borders)
    const int h0 = by * TILE - PADR;
    const int w0 = bx * TILE - PADR;
    for (int i = tid; i < 32 * 32; i += 256) {
        const int r = i >> 5, c = i & 31;
        const int gh = h0 + r, gw = w0 + c;
        float v = 0.f;
        if (gh >= 0 && gh < HTOT && gw >= 0 && gw < WTOT)
            v = x[gh * WTOT + gw];
        tile[r][c] = v;
    }
    __syncthreads();

    const unsigned int m = nsel;
    const int l  = tid & 15;                   // lane within quarter-wave
    const int qw = tid >> 4;                   // quarter-wave id

    int offs[18];
    #pragma unroll
    for (int j = 0; j < 18; ++j) {
        const int e = j * 16 + l;
        offs[j] = (e / 17) * LDSW + (e % 17);
    }

    float mn = 3.4e38f, mx = -3.4e38f;

    for (unsigned int s = qw; s < m; s += 16) {
        const int tp  = sel[s];
        const int ppy = tp >> 4, ppx = tp & 15;
        const float* __restrict__ kf   = fb + (size_t)sidx[tp] * 289;
        const float* __restrict__ base = &tile[ppy][ppx];

        float a0 = 0.f, a1 = 0.f, a2 = 0.f, a3 = 0.f;
        #pragma unroll
        for (int j = 0; j < 16; j += 4) {
            a0 = fmaf(kf[(j    ) * 16 + l], base[offs[j    ]], a0);
            a1 = fmaf(kf[(j + 1) * 16 + l], base[offs[j + 1]], a1);
            a2 = fmaf(kf[(j + 2) * 16 + l], base[offs[j + 2]], a2);
            a3 = fmaf(kf[(j + 3) * 16 + l], base[offs[j + 3]], a3);
        }
        a0 = fmaf(kf[16 * 16 + l], base[offs[16]], a0);
        a1 = fmaf(kf[17 * 16 + l], base[offs[17]], a1);
        float acc = (a0 + a1) + (a2 + a3);
        if (l == 0) acc = fmaf(kf[288], base[16 * LDSW + 16], acc);  // e = 288 tail

        #pragma unroll
        for (int off = 8; off; off >>= 1)
            acc += __shfl_xor(acc, off, 64);

        if (l == 0)
            y[(by * TILE + ppy) * WTOT + bx * TILE + ppx] = acc;
        mn = fminf(mn, acc);
        mx = fmaxf(mx, acc);
    }

    // ---- block min/max reduce, then ONE atomic pair into a spread cell ----
    #pragma unroll
    for (int off = 32; off > 0; off >>= 1) {
        mn = fminf(mn, __shfl_down(mn, off, 64));
        mx = fmaxf(mx, __shfl_down(mx, off, 64));
    }
    __shared__ float smn[4], smx[4];
    const int wid = tid >> 6, lane = tid & 63;
    if (lane == 0) { smn[wid] = mn; smx[wid] = mx; }
    __syncthreads();
    if (tid == 0) {
        float bmn = smn[0], bmx = smx[0];
        #pragma unroll
        for (int i = 1; i < 4; ++i) {
            bmn = fminf(bmn, smn[i]);
            bmx = fmaxf(bmx, smx[i]);
        }
        const int cell = (gid & (NCELL - 1)) * 16;      // 64-B stride
        atomicMin(&cells[cell], fenc(bmn));
        atomicMax(&cells[1024 + cell], fenc(bmx));      // 4096 B / 4
    }
}

// fold the 64 spread cells into plain floats {min, max}
__global__ void reduce_mm(const unsigned int* __restrict__ cells,
                          float* __restrict__ mmf)
{
    const int l = threadIdx.x;                 // 64 threads
    float mn = fdec(cells[l * 16]);
    float mx = fdec(cells[1024 + l * 16]);
    #pragma unroll
    for (int off = 32; off; off >>= 1) {
        mn = fminf(mn, __shfl_xor(mn, off, 64));
        mx = fmaxf(mx, __shfl_xor(mx, off, 64));
    }
    if (l == 0) { mmf[0] = mn; mmf[1] = mx; }
}

__global__ __launch_bounds__(256) void filter_final(
    float* __restrict__ y,
    const float* __restrict__ mmf)
{
    const int i = blockIdx.x * 256 + threadIdx.x;
    const float ymin = mmf[0];
    const float ymax = mmf[1];
    const float rng  = fmaxf(ymax - ymin, 1e-8f);

    const float v  = y[i];
    const float o1 = 100.f * (v - ymin) / rng;                     // in [0,100]
    const float s  = 100.f / (1.f + expf(-(TEMPERATURE * (o1 * 0.01f - THRESHOLD * 0.01f))));

    // analytic post-sigmoid extrema: o1 hits exactly 0 and 100 at argmin/argmax
    const float smin = 100.f / (1.f + expf( 11.f));   // 100*sigmoid(-11)
    const float smax = 100.f / (1.f + expf(-9.f));    // 100*sigmoid(+9)
    const float srng = fmaxf(smax - smin, 1e-8f);

    y[i] = 100.f * (s - smin) / srng;
}

extern "C" void kernel_launch(void* const* d_in, const int* in_sizes, int n_in,
                              void* d_out, int out_size, void* d_ws, size_t ws_size,
                              hipStream_t stream) {
    const float* x      = (const float*)d_in[0];
    const int*   freq   = (const int*)d_in[1];
    const int*   orient = (const int*)d_in[2];
    const float* fb     = (const float*)d_in[3];
    float*       out    = (float*)d_out;                 // doubles as y scratch
    unsigned int* cells = (unsigned int*)d_ws;           // spread min/max cells
    float*        mmf   = (float*)((char*)d_ws + 8192);  // final {min, max}

    // init: encoded-min cells -> 0xFFFFFFFF, encoded-max cells -> 0
    hipMemsetAsync(d_ws, 0xFF, 4096, stream);
    hipMemsetAsync((char*)d_ws + 4096, 0x00, 4096, stream);

    // 1024 tiles x 8 slices; consecutive gid = same tile across the 8 XCDs
    filter_sliced<<<dim3(1024 * NSLICE), 256, 0, stream>>>(x, freq, orient, fb, out, cells);

    reduce_mm<<<1, 64, 0, stream>>>(cells, mmf);

    filter_final<<<(HTOT * WTOT) / 256, 256, 0, stream>>>(out, mmf);
}

// Round 7
// 43.687 us; speedup vs baseline: 4.7428x; 1.0069x over previous
//
#include <hip/hip_runtime.h>
#include <math.h>

#define KSZ   17
#define PADR  8
#define FDIM  100
#define ODIM  180
#define HTOT  512
#define WTOT  512
#define TILE  16
#define LDSW  48
#define NSLICE 8
#define SLICE_SZ 2250      // 18000/8 -> 2.6 MB per slice, fits one XCD's 4 MiB L2
#define NBLK   (1024 * NSLICE)
#define TEMPERATURE 20.0f
#define THRESHOLD   55.0f

// ws layout (bytes):
//   [0, 65536)      : float2 partial[8192] — per-block {min, max}, all written every call
//   [65536, 65544)  : final float {min, max} written by reduce_mm
__global__ __launch_bounds__(256) void filter_sliced(
    const float* __restrict__ x,
    const int*   __restrict__ freq,
    const int*   __restrict__ orient,
    const float* __restrict__ fb,
    float*       __restrict__ y,
    float2*      __restrict__ partial)
{
    __shared__ float tile[2 * TILE][LDSW];     // 32 x 48 floats
    __shared__ int   sidx[256];                // per-pixel filter index
    __shared__ unsigned short sel[256];        // compacted list of my-slice pixels
    __shared__ unsigned int nsel;

    const int gid   = blockIdx.x;
    const int slice = gid & (NSLICE - 1);
    const int t     = gid >> 3;                // tile id 0..1023
    const int bx    = t & 31, by = t >> 5;
    const int tid   = threadIdx.x;
    const int px    = tid & 15, py = tid >> 4;

    const int pid = (by * TILE + py) * WTOT + bx * TILE + px;
    int f0 = freq[pid] - 1;
    int o0 = orient[pid] - 1;
    f0 = f0 < 0 ? 0 : (f0 > FDIM - 1 ? FDIM - 1 : f0);
    o0 = o0 < 0 ? 0 : (o0 > ODIM - 1 ? ODIM - 1 : o0);
    const int idx = f0 * ODIM + o0;
    sidx[tid] = idx;
    if (tid == 0) nsel = 0;
    __syncthreads();

    // compact the pixels belonging to this block's slice
    const int lo = slice * SLICE_SZ;
    if (idx >= lo && idx < lo + SLICE_SZ) {
        unsigned int s = atomicAdd(&nsel, 1u);
        sel[s] = (unsigned short)tid;
    }

    // stage 32x32 input region (zero-padded at image borders)
    const int h0 = by * TILE - PADR;
    const int w0 = bx * TILE - PADR;
    for (int i = tid; i < 32 * 32; i += 256) {
        const int r = i >> 5, c = i & 31;
        const int gh = h0 + r, gw = w0 + c;
        float v = 0.f;
        if (gh >= 0 && gh < HTOT && gw >= 0 && gw < WTOT)
            v = x[gh * WTOT + gw];
        tile[r][c] = v;
    }
    __syncthreads();

    const unsigned int m = nsel;
    const int l  = tid & 15;                   // lane within quarter-wave
    const int qw = tid >> 4;                   // quarter-wave id

    int offs[18];
    #pragma unroll
    for (int j = 0; j < 18; ++j) {
        const int e = j * 16 + l;
        offs[j] = (e / 17) * LDSW + (e % 17);
    }

    float mn = 3.4e38f, mx = -3.4e38f;

    for (unsigned int s = qw; s < m; s += 16) {
        const int tp  = sel[s];
        const int ppy = tp >> 4, ppx = tp & 15;
        const float* __restrict__ kf   = fb + (size_t)sidx[tp] * 289;
        const float* __restrict__ base = &tile[ppy][ppx];

        float a0 = 0.f, a1 = 0.f, a2 = 0.f, a3 = 0.f;
        #pragma unroll
        for (int j = 0; j < 16; j += 4) {
            a0 = fmaf(kf[(j    ) * 16 + l], base[offs[j    ]], a0);
            a1 = fmaf(kf[(j + 1) * 16 + l], base[offs[j + 1]], a1);
            a2 = fmaf(kf[(j + 2) * 16 + l], base[offs[j + 2]], a2);
            a3 = fmaf(kf[(j + 3) * 16 + l], base[offs[j + 3]], a3);
        }
        a0 = fmaf(kf[16 * 16 + l], base[offs[16]], a0);
        a1 = fmaf(kf[17 * 16 + l], base[offs[17]], a1);
        float acc = (a0 + a1) + (a2 + a3);
        if (l == 0) acc = fmaf(kf[288], base[16 * LDSW + 16], acc);  // e = 288 tail

        #pragma unroll
        for (int off = 8; off; off >>= 1)
            acc += __shfl_xor(acc, off, 64);

        if (l == 0)
            y[(by * TILE + ppy) * WTOT + bx * TILE + ppx] = acc;
        mn = fminf(mn, acc);
        mx = fmaxf(mx, acc);
    }

    // ---- block min/max reduce, then ONE plain store to a unique slot ----
    #pragma unroll
    for (int off = 32; off > 0; off >>= 1) {
        mn = fminf(mn, __shfl_down(mn, off, 64));
        mx = fmaxf(mx, __shfl_down(mx, off, 64));
    }
    __shared__ float smn[4], smx[4];
    const int wid = tid >> 6, lane = tid & 63;
    if (lane == 0) { smn[wid] = mn; smx[wid] = mx; }
    __syncthreads();
    if (tid == 0) {
        float bmn = smn[0], bmx = smx[0];
        #pragma unroll
        for (int i = 1; i < 4; ++i) {
            bmn = fminf(bmn, smn[i]);
            bmx = fmaxf(bmx, smx[i]);
        }
        partial[gid] = make_float2(bmn, bmx);
    }
}

// fold the 8192 per-block partials into plain floats {min, max}
__global__ __launch_bounds__(256) void reduce_mm(
    const float2* __restrict__ partial,
    float* __restrict__ mmf)
{
    const int tid = threadIdx.x;
    float mn = 3.4e38f, mx = -3.4e38f;
    for (int i = tid; i < NBLK; i += 256) {
        const float2 p = partial[i];
        mn = fminf(mn, p.x);
        mx = fmaxf(mx, p.y);
    }
    #pragma unroll
    for (int off = 32; off > 0; off >>= 1) {
        mn = fminf(mn, __shfl_down(mn, off, 64));
        mx = fmaxf(mx, __shfl_down(mx, off, 64));
    }
    __shared__ float smn[4], smx[4];
    const int wid = tid >> 6, lane = tid & 63;
    if (lane == 0) { smn[wid] = mn; smx[wid] = mx; }
    __syncthreads();
    if (tid == 0) {
        float bmn = smn[0], bmx = smx[0];
        #pragma unroll
        for (int i = 1; i < 4; ++i) {
            bmn = fminf(bmn, smn[i]);
            bmx = fmaxf(bmx, smx[i]);
        }
        mmf[0] = bmn;
        mmf[1] = bmx;
    }
}

__global__ __launch_bounds__(256) void filter_final(
    float* __restrict__ y,
    const float* __restrict__ mmf)
{
    const int i = blockIdx.x * 256 + threadIdx.x;
    const float ymin = mmf[0];
    const float ymax = mmf[1];
    const float rng  = fmaxf(ymax - ymin, 1e-8f);

    const float v  = y[i];
    const float o1 = 100.f * (v - ymin) / rng;                     // in [0,100]
    const float s  = 100.f / (1.f + expf(-(TEMPERATURE * (o1 * 0.01f - THRESHOLD * 0.01f))));

    // analytic post-sigmoid extrema: o1 hits exactly 0 and 100 at argmin/argmax
    const float smin = 100.f / (1.f + expf( 11.f));   // 100*sigmoid(-11)
    const float smax = 100.f / (1.f + expf(-9.f));    // 100*sigmoid(+9)
    const float srng = fmaxf(smax - smin, 1e-8f);

    y[i] = 100.f * (s - smin) / srng;
}

extern "C" void kernel_launch(void* const* d_in, const int* in_sizes, int n_in,
                              void* d_out, int out_size, void* d_ws, size_t ws_size,
                              hipStream_t stream) {
    const float* x      = (const float*)d_in[0];
    const int*   freq   = (const int*)d_in[1];
    const int*   orient = (const int*)d_in[2];
    const float* fb     = (const float*)d_in[3];
    float*       out    = (float*)d_out;                  // doubles as y scratch
    float2*      partial = (float2*)d_ws;                 // 8192 per-block {min,max}
    float*       mmf    = (float*)((char*)d_ws + 65536);  // final {min, max}

    // 1024 tiles x 8 slices; consecutive gid = same tile across the 8 XCDs
    filter_sliced<<<dim3(NBLK), 256, 0, stream>>>(x, freq, orient, fb, out, partial);

    reduce_mm<<<1, 256, 0, stream>>>(partial, mmf);

    filter_final<<<(HTOT * WTOT) / 256, 256, 0, stream>>>(out, mmf);
}

// Round 8
// 34.875 us; speedup vs baseline: 5.9412x; 1.2527x over previous
//
#include <hip/hip_runtime.h>
#include <math.h>

#define FDIM  100
#define ODIM  180
#define HTOT  512
#define WTOT  512
#define TILE  32               // 32x32 pixel tile per (tile,slice) block
#define REG   48               // staged region = TILE + 16
#define LDSW  49
#define NSLICE 8
#define SLICE_SZ 2250          // 18000/8 -> 2.6 MB slice, fits one XCD's 4 MiB L2
#define NTILE 256              // (512/32)^2
#define NBLK  (NTILE * NSLICE) // 2048 blocks
#define TEMPERATURE 20.0f
#define THRESHOLD   55.0f

// ws layout (bytes):
//   [0, 16384)      : float2 partial[2048] — per-block {min, max}, all written every call
//   [16384, 16392)  : final float {min, max} written by reduce_mm
__global__ __launch_bounds__(256) void filter_sliced(
    const float* __restrict__ x,
    const int*   __restrict__ freq,
    const int*   __restrict__ orient,
    const float* __restrict__ fb,
    float*       __restrict__ y,
    float2*      __restrict__ partial)
{
    __shared__ float tile[REG][LDSW];          // 48 x 49 floats = 9408 B
    __shared__ int   sidx[TILE * TILE];        // 4096 B
    __shared__ unsigned short sel[TILE * TILE];// 2048 B (worst case safe)
    __shared__ unsigned int nsel;

    const int gid   = blockIdx.x;
    const int slice = gid & (NSLICE - 1);
    const int t     = gid >> 3;                // tile id 0..255
    const int bx    = t & 15, by = t >> 4;
    const int tid   = threadIdx.x;

    if (tid == 0) nsel = 0;
    __syncthreads();

    // pass 1: per-pixel filter index + compaction of this slice's pixels (4 px/thread)
    const int lo = slice * SLICE_SZ;
    #pragma unroll
    for (int k = 0; k < 4; ++k) {
        const int p  = tid + k * 256;
        const int pr = p >> 5, pc = p & 31;
        const int pid = (by * TILE + pr) * WTOT + bx * TILE + pc;
        int f0 = freq[pid] - 1;
        int o0 = orient[pid] - 1;
        f0 = f0 < 0 ? 0 : (f0 > FDIM - 1 ? FDIM - 1 : f0);
        o0 = o0 < 0 ? 0 : (o0 > ODIM - 1 ? ODIM - 1 : o0);
        const int idx = f0 * ODIM + o0;
        sidx[p] = idx;
        if (idx >= lo && idx < lo + SLICE_SZ) {
            unsigned int s = atomicAdd(&nsel, 1u);
            sel[s] = (unsigned short)p;
        }
    }

    // stage 48x48 input region (zero-padded at image borders)
    const int h0 = by * TILE - 8;
    const int w0 = bx * TILE - 8;
    for (int i = tid; i < REG * REG; i += 256) {
        const int r = i / REG, c = i - r * REG;
        const int gh = h0 + r, gw = w0 + c;
        float v = 0.f;
        if (gh >= 0 && gh < HTOT && gw >= 0 && gw < WTOT)
            v = x[gh * WTOT + gw];
        tile[r][c] = v;
    }
    __syncthreads();

    const unsigned int m = nsel;
    const int l  = tid & 15;                   // lane within quarter-wave
    const int qw = tid >> 4;                   // quarter-wave id

    int offs[18];
    #pragma unroll
    for (int j = 0; j < 18; ++j) {
        const int e = j * 16 + l;
        offs[j] = (e / 17) * LDSW + (e % 17);
    }

    float mn = 3.4e38f, mx = -3.4e38f;

    // each quarter-wave takes every 16th selected pixel (avg ~8 each)
    for (unsigned int s = qw; s < m; s += 16) {
        const int tp  = sel[s];
        const int ppy = tp >> 5, ppx = tp & 31;
        const float* __restrict__ kf = fb + (size_t)sidx[tp] * 289;

        // issue all 19 filter loads first (MLP), then the LDS/FMA chain
        float kv[18];
        #pragma unroll
        for (int j = 0; j < 18; ++j) kv[j] = kf[j * 16 + l];
        const float kt = kf[288];

        const float* __restrict__ base = &tile[ppy][ppx];
        float a0 = 0.f, a1 = 0.f, a2 = 0.f, a3 = 0.f;
        #pragma unroll
        for (int j = 0; j < 16; j += 4) {
            a0 = fmaf(kv[j    ], base[offs[j    ]], a0);
            a1 = fmaf(kv[j + 1], base[offs[j + 1]], a1);
            a2 = fmaf(kv[j + 2], base[offs[j + 2]], a2);
            a3 = fmaf(kv[j + 3], base[offs[j + 3]], a3);
        }
        a0 = fmaf(kv[16], base[offs[16]], a0);
        a1 = fmaf(kv[17], base[offs[17]], a1);
        float acc = (a0 + a1) + (a2 + a3);
        if (l == 0) acc = fmaf(kt, base[16 * LDSW + 16], acc);  // e = 288 tail

        // butterfly sum over the 16-lane group
        #pragma unroll
        for (int off = 8; off; off >>= 1)
            acc += __shfl_xor(acc, off, 64);

        if (l == 0)
            y[(by * TILE + ppy) * WTOT + bx * TILE + ppx] = acc;
        mn = fminf(mn, acc);
        mx = fmaxf(mx, acc);
    }

    // ---- block min/max reduce, then ONE plain store to a unique slot ----
    #pragma unroll
    for (int off = 32; off > 0; off >>= 1) {
        mn = fminf(mn, __shfl_down(mn, off, 64));
        mx = fmaxf(mx, __shfl_down(mx, off, 64));
    }
    __shared__ float smn[4], smx[4];
    const int wid = tid >> 6, lane = tid & 63;
    if (lane == 0) { smn[wid] = mn; smx[wid] = mx; }
    __syncthreads();
    if (tid == 0) {
        float bmn = smn[0], bmx = smx[0];
        #pragma unroll
        for (int i = 1; i < 4; ++i) {
            bmn = fminf(bmn, smn[i]);
            bmx = fmaxf(bmx, smx[i]);
        }
        partial[gid] = make_float2(bmn, bmx);
    }
}

// fold the 2048 per-block partials into plain floats {min, max}
__global__ __launch_bounds__(256) void reduce_mm(
    const float2* __restrict__ partial,
    float* __restrict__ mmf)
{
    const int tid = threadIdx.x;
    float mn = 3.4e38f, mx = -3.4e38f;
    for (int i = tid; i < NBLK; i += 256) {
        const float2 p = partial[i];
        mn = fminf(mn, p.x);
        mx = fmaxf(mx, p.y);
    }
    #pragma unroll
    for (int off = 32; off > 0; off >>= 1) {
        mn = fminf(mn, __shfl_down(mn, off, 64));
        mx = fmaxf(mx, __shfl_down(mx, off, 64));
    }
    __shared__ float smn[4], smx[4];
    const int wid = tid >> 6, lane = tid & 63;
    if (lane == 0) { smn[wid] = mn; smx[wid] = mx; }
    __syncthreads();
    if (tid == 0) {
        float bmn = smn[0], bmx = smx[0];
        #pragma unroll
        for (int i = 1; i < 4; ++i) {
            bmn = fminf(bmn, smn[i]);
            bmx = fmaxf(bmx, smx[i]);
        }
        mmf[0] = bmn;
        mmf[1] = bmx;
    }
}

__global__ __launch_bounds__(256) void filter_final(
    float* __restrict__ y,
    const float* __restrict__ mmf)
{
    const int i = blockIdx.x * 256 + threadIdx.x;
    const float ymin = mmf[0];
    const float ymax = mmf[1];
    const float rng  = fmaxf(ymax - ymin, 1e-8f);

    const float v  = y[i];
    const float o1 = 100.f * (v - ymin) / rng;                     // in [0,100]
    const float s  = 100.f / (1.f + expf(-(TEMPERATURE * (o1 * 0.01f - THRESHOLD * 0.01f))));

    // analytic post-sigmoid extrema: o1 hits exactly 0 and 100 at argmin/argmax
    const float smin = 100.f / (1.f + expf( 11.f));   // 100*sigmoid(-11)
    const float smax = 100.f / (1.f + expf(-9.f));    // 100*sigmoid(+9)
    const float srng = fmaxf(smax - smin, 1e-8f);

    y[i] = 100.f * (s - smin) / srng;
}

extern "C" void kernel_launch(void* const* d_in, const int* in_sizes, int n_in,
                              void* d_out, int out_size, void* d_ws, size_t ws_size,
                              hipStream_t stream) {
    const float* x      = (const float*)d_in[0];
    const int*   freq   = (const int*)d_in[1];
    const int*   orient = (const int*)d_in[2];
    const float* fb     = (const float*)d_in[3];
    float*       out    = (float*)d_out;                  // doubles as y scratch
    float2*      partial = (float2*)d_ws;                 // 2048 per-block {min,max}
    float*       mmf    = (float*)((char*)d_ws + 16384);  // final {min, max}

    // 256 tiles x 8 slices; consecutive gid = same tile across the 8 XCDs
    filter_sliced<<<dim3(NBLK), 256, 0, stream>>>(x, freq, orient, fb, out, partial);

    reduce_mm<<<1, 256, 0, stream>>>(partial, mmf);

    filter_final<<<(HTOT * WTOT) / 256, 256, 0, stream>>>(out, mmf);
}